// Round 1
// baseline (2085.543 us; speedup 1.0000x reference)
//
#include <hip/hip_runtime.h>
#include <math.h>

// Problem constants
#define NG   512      // graphs
#define NPG  128      // nodes/graph
#define NN   65536    // nodes
#define DD   512      // feature dim
#define KK   1024     // codebook
#define HH   128      // hidden
#define TT   10       // classes

// Output layout (element offsets, fp32)
static const long OFF_CPRE = 0;                       // [512,10]
static const long OFF_KPRE = 5120;                    // [512,10]
static const long OFF_YPRE = 10240;                   // [512,10]
static const long OFF_AORI = 15360;                   // [512,128,128]
static const long OFF_AREC = OFF_AORI + 8388608L;     // [512,128,128]
static const long OFF_Z    = OFF_AREC + 8388608L;     // [65536,512]
static const long OFF_X    = OFF_Z + 33554432L;       // [65536,512]
static const long OFF_CD   = OFF_X + 33554432L;       // [1024,1024]
static const long OFF_CM   = OFF_CD + 1048576L;       // [1024,1024]
static const long OFF_PC   = OFF_CM + 1048576L;       // [512,512]
static const long OFF_PX   = OFF_PC + 262144L;        // [512,512]

// Scratch inside A_ori region (overwritten by k_adj(A_ori) at the very end)
//  h:131072  cs:524288  tmp2:524288  ccb:524288  kcb:524288  cn2:1024
//  idx:65536(int)  pk:262144  dv:1024    (total < 8388608)
// ct (codebook_transformed) lives in the A_rec region until gather is done.

__device__ __forceinline__ float sigm_fast(float v) { return 1.0f / (1.0f + __expf(-v)); }
__device__ __forceinline__ float sigm_acc (float v) { return 1.0f / (1.0f + expf(-v)); }

// ---- diag/off-diag masks + diag vector --------------------------------------
__global__ void k_diagmask(const float* __restrict__ causal,
                           float* __restrict__ cd, float* __restrict__ cm,
                           float* __restrict__ dv) {
  int i = blockIdx.x * 256 + threadIdx.x;      // over K*K
  int r = i >> 10, c = i & 1023;
  float v = causal[i];
  bool diag = (r == c);
  cd[i] = diag ? v : 0.0f;
  cm[i] = diag ? 0.0f : v;
  if (diag) dv[r] = v;
}

// ---- fc1: h = sigmoid(cbi @ fc1_w^T + b)  [1024,128] ------------------------
__global__ void k_fc1(const float* __restrict__ cbi, const float* __restrict__ w,
                      const float* __restrict__ b, float* __restrict__ h) {
  int i = blockIdx.x * 256 + threadIdx.x;      // 131072
  int k = i >> 7, j = i & 127;
  const float4* xr = (const float4*)(cbi + (long)k * DD);
  const float4* wr = (const float4*)(w + (long)j * DD);
  float s = b[j];
  for (int d = 0; d < DD / 4; d++) {
    float4 a = xr[d], bb = wr[d];
    s += a.x * bb.x + a.y * bb.y + a.z * bb.z + a.w * bb.w;
  }
  h[i] = sigm_acc(s);
}

// ---- fc2: ct = h @ fc2_w^T + b ; cs = sigmoid(ct)  [1024,512] ---------------
__global__ void k_fc2(const float* __restrict__ h, const float* __restrict__ w,
                      const float* __restrict__ b, float* __restrict__ ct,
                      float* __restrict__ cs) {
  int i = blockIdx.x * 256 + threadIdx.x;      // 524288
  int k = i >> 9, d = i & 511;
  const float4* hr = (const float4*)(h + (long)k * HH);
  const float4* wr = (const float4*)(w + (long)d * HH);
  float s = b[d];
  for (int j = 0; j < HH / 4; j++) {
    float4 a = hr[j], bb = wr[j];
    s += a.x * bb.x + a.y * bb.y + a.z * bb.z + a.w * bb.w;
  }
  ct[i] = s;
  cs[i] = sigm_acc(s);
}

// ---- generic tiled SGEMM: C[M,Nc] = Af(A) @ Bf(B) ---------------------------
// AM: 0 plain, 1 CE (off-diag(A)+I), 2 CM (off-diag(A))
// BM: 0 plain, 1 row-scale by dscale[j]
template <int AM, int BM>
__launch_bounds__(256)
__global__ void gemm64(const float* __restrict__ A, const float* __restrict__ B,
                       const float* __restrict__ dscale, float* __restrict__ C,
                       int M, int Nc, int Kr) {
  __shared__ __align__(16) float as[32][68];   // [kr][m]
  __shared__ __align__(16) float bs[32][68];   // [kr][n]
  int tid = threadIdx.x;
  int tx = tid & 15, ty = tid >> 4;
  int m0 = blockIdx.y * 64, n0 = blockIdx.x * 64;
  float acc[4][4] = {};
  for (int kt = 0; kt < Kr; kt += 32) {
    // stage A tile (64 m x 32 kr), transposed into as[kr][m]
    for (int s = tid; s < 512; s += 256) {
      int m = s >> 3, c4 = (s & 7) << 2;
      int gr = m0 + m, gc = kt + c4;
      float4 v = *(const float4*)&A[(long)gr * Kr + gc];
      float vv[4] = {v.x, v.y, v.z, v.w};
      if (AM == 1) {
#pragma unroll
        for (int q = 0; q < 4; q++) if (gc + q == gr) vv[q] = 1.0f;
      } else if (AM == 2) {
#pragma unroll
        for (int q = 0; q < 4; q++) if (gc + q == gr) vv[q] = 0.0f;
      }
      as[c4 + 0][m] = vv[0]; as[c4 + 1][m] = vv[1];
      as[c4 + 2][m] = vv[2]; as[c4 + 3][m] = vv[3];
    }
    // stage B tile (32 kr x 64 n)
    for (int s = tid; s < 512; s += 256) {
      int r = s >> 4, c4 = (s & 15) << 2;
      float4 v = *(const float4*)&B[(long)(kt + r) * Nc + n0 + c4];
      if (BM == 1) {
        float sc = dscale[kt + r];
        v.x *= sc; v.y *= sc; v.z *= sc; v.w *= sc;
      }
      *(float4*)&bs[r][c4] = v;
    }
    __syncthreads();
#pragma unroll
    for (int r = 0; r < 32; r++) {
      float4 a4 = *(const float4*)&as[r][ty * 4];
      float4 b4 = *(const float4*)&bs[r][tx * 4];
      float av[4] = {a4.x, a4.y, a4.z, a4.w};
      float bv[4] = {b4.x, b4.y, b4.z, b4.w};
#pragma unroll
      for (int i = 0; i < 4; i++)
#pragma unroll
        for (int j = 0; j < 4; j++) acc[i][j] += av[i] * bv[j];
    }
    __syncthreads();
  }
#pragma unroll
  for (int i = 0; i < 4; i++) {
    float4 v = make_float4(acc[i][0], acc[i][1], acc[i][2], acc[i][3]);
    *(float4*)&C[(long)(m0 + ty * 4 + i) * Nc + n0 + tx * 4] = v;
  }
}

// ---- row sum-of-squares of ccb -> cn2[1024] ---------------------------------
__global__ void k_cnorm(const float* __restrict__ ccb, float* __restrict__ cn2) {
  int row = blockIdx.x * 4 + (threadIdx.x >> 6);
  int lane = threadIdx.x & 63;
  const float* r = ccb + (long)row * DD;
  float s = 0.0f;
  for (int q = 0; q < DD; q += 64) { float v = r[lane + q]; s += v * v; }
  for (int off = 32; off > 0; off >>= 1) s += __shfl_down(s, off);
  if (lane == 0) cn2[row] = s;
}

// ---- fused distance-GEMM + argmin: idx[n] = argmin_k (cn2[k] - 2 x_n.c_k) ---
__launch_bounds__(256)
__global__ void k_argmin(const float* __restrict__ x, const float* __restrict__ ccb,
                         const float* __restrict__ cn2, int* __restrict__ idxg) {
  __shared__ __align__(16) float xs[32][68];    // [d][node]
  __shared__ __align__(16) float cbs[32][68];   // [d][k]
  __shared__ float rmin[64][17];
  __shared__ int   ridx[64][17];
  int tid = threadIdx.x;
  int tx = tid & 15, ty = tid >> 4;
  long n0 = (long)blockIdx.x * 64;
  float minv[4]; int mini[4];
#pragma unroll
  for (int i = 0; i < 4; i++) { minv[i] = 3.4e38f; mini[i] = 0; }
  for (int kt = 0; kt < KK; kt += 64) {
    float acc[4][4] = {};
    for (int dt = 0; dt < DD; dt += 32) {
      for (int s = tid; s < 512; s += 256) {
        int m = s >> 3, c4 = (s & 7) << 2;
        float4 v = *(const float4*)&x[(n0 + m) * DD + dt + c4];
        xs[c4 + 0][m] = v.x; xs[c4 + 1][m] = v.y;
        xs[c4 + 2][m] = v.z; xs[c4 + 3][m] = v.w;
      }
      for (int s = tid; s < 512; s += 256) {
        int m = s >> 3, c4 = (s & 7) << 2;
        float4 v = *(const float4*)&ccb[(long)(kt + m) * DD + dt + c4];
        cbs[c4 + 0][m] = v.x; cbs[c4 + 1][m] = v.y;
        cbs[c4 + 2][m] = v.z; cbs[c4 + 3][m] = v.w;
      }
      __syncthreads();
#pragma unroll
      for (int r = 0; r < 32; r++) {
        float4 a4 = *(const float4*)&xs[r][ty * 4];
        float4 b4 = *(const float4*)&cbs[r][tx * 4];
        float av[4] = {a4.x, a4.y, a4.z, a4.w};
        float bv[4] = {b4.x, b4.y, b4.z, b4.w};
#pragma unroll
        for (int i = 0; i < 4; i++)
#pragma unroll
          for (int j = 0; j < 4; j++) acc[i][j] += av[i] * bv[j];
      }
      __syncthreads();
    }
#pragma unroll
    for (int j = 0; j < 4; j++) {
      int kg = kt + tx * 4 + j;
      float c2 = cn2[kg];
#pragma unroll
      for (int i = 0; i < 4; i++) {
        float v = c2 - 2.0f * acc[i][j];
        if (v < minv[i]) { minv[i] = v; mini[i] = kg; }
      }
    }
  }
#pragma unroll
  for (int i = 0; i < 4; i++) { rmin[ty * 4 + i][tx] = minv[i]; ridx[ty * 4 + i][tx] = mini[i]; }
  __syncthreads();
  if (tid < 64) {
    float bv = rmin[tid][0]; int bi = ridx[tid][0];
    for (int t = 1; t < 16; t++) {
      float v = rmin[tid][t]; int ii = ridx[tid][t];
      if (v < bv || (v == bv && ii < bi)) { bv = v; bi = ii; }
    }
    idxg[n0 + tid] = bi;
  }
}

// ---- z gather: z[n,:] = ct[idx[n],:] ----------------------------------------
__global__ void k_gather(const float4* __restrict__ ct4, const int* __restrict__ idxg,
                         float4* __restrict__ z4) {
  long i = (long)blockIdx.x * 256 + threadIdx.x;  // over NN*128 float4
  int n = (int)(i >> 7), c = (int)(i & 127);
  z4[i] = ct4[(long)idxg[n] * 128 + c];
}

// ---- pooled means -----------------------------------------------------------
__global__ void k_pool(const float* __restrict__ x, const float* __restrict__ ccb,
                       const float* __restrict__ kcb, const int* __restrict__ idxg,
                       float* __restrict__ px, float* __restrict__ pc,
                       float* __restrict__ pk) {
  __shared__ int sidx[NPG];
  int g = blockIdx.x, tid = threadIdx.x;   // 512 threads
  if (tid < NPG) sidx[tid] = idxg[g * NPG + tid];
  __syncthreads();
  int d = tid;
  float sx = 0.0f, sc = 0.0f, sk = 0.0f;
  for (int n = 0; n < NPG; n++) {
    sx += x[((long)g * NPG + n) * DD + d];
    long r = (long)sidx[n] * DD + d;
    sc += ccb[r]; sk += kcb[r];
  }
  px[(long)g * DD + d] = sx / 128.0f;
  pc[(long)g * DD + d] = (sx + sc) / 128.0f;
  pk[(long)g * DD + d] = sk / 128.0f;
}

// ---- classifier heads -------------------------------------------------------
__global__ void k_heads(const float* __restrict__ pc, const float* __restrict__ pk,
                        const float* __restrict__ px, const float* __restrict__ w,
                        const float* __restrict__ b, float* __restrict__ cpre,
                        float* __restrict__ kpre, float* __restrict__ ypre) {
  int g = blockIdx.x, t = threadIdx.x;   // 64 threads, 30 active
  if (t >= 30) return;
  int which = t / 10, tt = t % 10;
  const float* src = (which == 0) ? pc : ((which == 1) ? pk : px);
  const float* sr = src + (long)g * DD;
  const float* wr = w + (long)tt * DD;
  float s = 0.0f;
  for (int d = 0; d < DD; d++) s += sr[d] * wr[d];
  s += b[tt];
  float* dst = (which == 0) ? cpre : ((which == 1) ? kpre : ypre);
  dst[g * TT + tt] = s;
}

// ---- x passthrough ----------------------------------------------------------
__global__ void k_copy(const float4* __restrict__ src, float4* __restrict__ dst) {
  long i = (long)blockIdx.x * 256 + threadIdx.x;
  dst[i] = src[i];
}

// ---- per-graph adjacency: sigmoid(norm(Z) @ norm(Z)^T / 0.1) ----------------
__launch_bounds__(256)
__global__ void k_adj(const float* __restrict__ Z, float* __restrict__ Aout) {
  __shared__ float nrm[NPG];
  __shared__ float inv[NPG];
  __shared__ __align__(16) float zs[32][132];  // [d][node]
  int tid = threadIdx.x;
  int g = blockIdx.x;
  const float* base = Z + (long)g * NPG * DD;
  if (tid < NPG) nrm[tid] = 0.0f;
  __syncthreads();
  // phase A: row sumsq (two waves per row, wave-reduce, LDS atomic combine)
  for (int k = 0; k < 64; k++) {
    long i = (long)k * 256 + tid;                 // float4 index, 16384 total
    int n = (int)(i >> 7);
    float4 v = ((const float4*)base)[i];
    float s = v.x * v.x + v.y * v.y + v.z * v.z + v.w * v.w;
    for (int off = 32; off > 0; off >>= 1) s += __shfl_down(s, off);
    if ((tid & 63) == 0) atomicAdd(&nrm[n], s);
  }
  __syncthreads();
  if (tid < NPG) inv[tid] = 1.0f / fmaxf(sqrtf(nrm[tid]), 1e-12f);
  __syncthreads();
  // phase B: tiled cosine GEMM
  float acc[8][8] = {};
  int tx = tid & 15, ty = tid >> 4;
  for (int dt = 0; dt < DD; dt += 32) {
    for (int s = tid; s < 1024; s += 256) {       // 128 nodes x 8 float4
      int n = s >> 3, c4 = (s & 7) << 2;
      float4 v = *(const float4*)&base[(long)n * DD + dt + c4];
      float iv = inv[n];
      zs[c4 + 0][n] = v.x * iv; zs[c4 + 1][n] = v.y * iv;
      zs[c4 + 2][n] = v.z * iv; zs[c4 + 3][n] = v.w * iv;
    }
    __syncthreads();
#pragma unroll 8
    for (int r = 0; r < 32; r++) {
      float rv[8], cv[8];
      *(float4*)&rv[0] = *(const float4*)&zs[r][ty * 8];
      *(float4*)&rv[4] = *(const float4*)&zs[r][ty * 8 + 4];
      *(float4*)&cv[0] = *(const float4*)&zs[r][tx * 8];
      *(float4*)&cv[4] = *(const float4*)&zs[r][tx * 8 + 4];
#pragma unroll
      for (int i = 0; i < 8; i++)
#pragma unroll
        for (int j = 0; j < 8; j++) acc[i][j] += rv[i] * cv[j];
    }
    __syncthreads();
  }
  float* aout = Aout + (long)g * NPG * NPG;
#pragma unroll
  for (int i = 0; i < 8; i++) {
    int rr = ty * 8 + i;
    float o[8];
#pragma unroll
    for (int j = 0; j < 8; j++) o[j] = sigm_fast(acc[i][j] * 10.0f);
    *(float4*)&aout[(long)rr * NPG + tx * 8]     = make_float4(o[0], o[1], o[2], o[3]);
    *(float4*)&aout[(long)rr * NPG + tx * 8 + 4] = make_float4(o[4], o[5], o[6], o[7]);
  }
}

extern "C" void kernel_launch(void* const* d_in, const int* in_sizes, int n_in,
                              void* d_out, int out_size, void* d_ws, size_t ws_size,
                              hipStream_t stream) {
  const float* x      = (const float*)d_in[0];
  // d_in[1] (batch) is deterministic repeat(arange(G),128): unused.
  const float* cbi    = (const float*)d_in[2];
  const float* fc1w   = (const float*)d_in[3];
  const float* fc1b   = (const float*)d_in[4];
  const float* fc2w   = (const float*)d_in[5];
  const float* fc2b   = (const float*)d_in[6];
  const float* causal = (const float*)d_in[7];
  const float* clsw   = (const float*)d_in[8];
  const float* clsb   = (const float*)d_in[9];
  float* out = (float*)d_out;

  float* cpre = out + OFF_CPRE;
  float* kpre = out + OFF_KPRE;
  float* ypre = out + OFF_YPRE;

  // scratch carved out of the A_ori region (overwritten last)
  float* scr  = out + OFF_AORI;
  float* h    = scr;
  float* cs   = scr + 131072L;
  float* tmp2 = scr + 655360L;
  float* ccb  = scr + 1179648L;
  float* kcb  = scr + 1703936L;
  float* cn2  = scr + 2228224L;
  int*   idxg = (int*)(scr + 2229248L);
  float* pk   = scr + 2294784L;
  float* dv   = scr + 2556928L;
  float* ct   = out + OFF_AREC;   // lives in A_rec region until gather done

  k_diagmask<<<4096, 256, 0, stream>>>(causal, out + OFF_CD, out + OFF_CM, dv);
  k_fc1<<<512, 256, 0, stream>>>(cbi, fc1w, fc1b, h);
  k_fc2<<<2048, 256, 0, stream>>>(h, fc2w, fc2b, ct, cs);
  gemm64<2, 0><<<dim3(8, 16), 256, 0, stream>>>(causal, cs,   nullptr, tmp2, KK, DD, KK);
  gemm64<1, 1><<<dim3(8, 16), 256, 0, stream>>>(causal, cs,   dv,      ccb,  KK, DD, KK);
  gemm64<1, 0><<<dim3(8, 16), 256, 0, stream>>>(causal, tmp2, nullptr, kcb,  KK, DD, KK);
  k_cnorm<<<256, 256, 0, stream>>>(ccb, cn2);
  k_argmin<<<1024, 256, 0, stream>>>(x, ccb, cn2, idxg);
  k_gather<<<32768, 256, 0, stream>>>((const float4*)ct, idxg, (float4*)(out + OFF_Z));
  k_pool<<<512, 512, 0, stream>>>(x, ccb, kcb, idxg, out + OFF_PX, out + OFF_PC, pk);
  k_heads<<<512, 64, 0, stream>>>(out + OFF_PC, pk, out + OFF_PX, clsw, clsb, cpre, kpre, ypre);
  k_copy<<<32768, 256, 0, stream>>>((const float4*)x, (float4*)(out + OFF_X));
  k_adj<<<512, 256, 0, stream>>>(out + OFF_Z, out + OFF_AREC);  // overwrites ct (done)
  k_adj<<<512, 256, 0, stream>>>(x, out + OFF_AORI);            // overwrites scratch (done)
}

// Round 2
// 1824.570 us; speedup vs baseline: 1.1430x; 1.1430x over previous
//
#include <hip/hip_runtime.h>
#include <math.h>

// Problem constants
#define NG   512      // graphs
#define NPG  128      // nodes/graph
#define NN   65536    // nodes
#define DD   512      // feature dim
#define KK   1024     // codebook
#define HH   128      // hidden
#define TT   10       // classes

#define RES_TAU 1.0f  // rescue margin threshold (approx d2 error bound ~0.03; 30x safety)
#define RES_CAP 65536

typedef __attribute__((ext_vector_type(8))) short short8;
typedef __attribute__((ext_vector_type(4))) float float4v;

// Output layout (element offsets, fp32)
static const long OFF_CPRE = 0;                       // [512,10]
static const long OFF_KPRE = 5120;                    // [512,10]
static const long OFF_YPRE = 10240;                   // [512,10]
static const long OFF_AORI = 15360;                   // [512,128,128]
static const long OFF_AREC = OFF_AORI + 8388608L;     // [512,128,128]
static const long OFF_Z    = OFF_AREC + 8388608L;     // [65536,512]
static const long OFF_X    = OFF_Z + 33554432L;       // [65536,512]
static const long OFF_CD   = OFF_X + 33554432L;       // [1024,1024]
static const long OFF_CM   = OFF_CD + 1048576L;       // [1024,1024]
static const long OFF_PC   = OFF_CM + 1048576L;       // [512,512]
static const long OFF_PX   = OFF_PC + 262144L;        // [512,512]

__device__ __forceinline__ float sigm_fast(float v) { return 1.0f / (1.0f + __expf(-v)); }
__device__ __forceinline__ float sigm_acc (float v) { return 1.0f / (1.0f + expf(-v)); }

// ---- diag/off-diag masks + diag vector --------------------------------------
__global__ void k_diagmask(const float* __restrict__ causal,
                           float* __restrict__ cd, float* __restrict__ cm,
                           float* __restrict__ dv) {
  int i = blockIdx.x * 256 + threadIdx.x;      // over K*K
  int r = i >> 10, c = i & 1023;
  float v = causal[i];
  bool diag = (r == c);
  cd[i] = diag ? v : 0.0f;
  cm[i] = diag ? 0.0f : v;
  if (diag) dv[r] = v;
}

// ---- fc1: h = sigmoid(cbi @ fc1_w^T + b)  [1024,128] ------------------------
__global__ void k_fc1(const float* __restrict__ cbi, const float* __restrict__ w,
                      const float* __restrict__ b, float* __restrict__ h) {
  int i = blockIdx.x * 256 + threadIdx.x;      // 131072
  int k = i >> 7, j = i & 127;
  const float4* xr = (const float4*)(cbi + (long)k * DD);
  const float4* wr = (const float4*)(w + (long)j * DD);
  float s = b[j];
  for (int d = 0; d < DD / 4; d++) {
    float4 a = xr[d], bb = wr[d];
    s += a.x * bb.x + a.y * bb.y + a.z * bb.z + a.w * bb.w;
  }
  h[i] = sigm_acc(s);
}

// ---- fc2: ct = h @ fc2_w^T + b ; cs = sigmoid(ct)  [1024,512] ---------------
__global__ void k_fc2(const float* __restrict__ h, const float* __restrict__ w,
                      const float* __restrict__ b, float* __restrict__ ct,
                      float* __restrict__ cs) {
  int i = blockIdx.x * 256 + threadIdx.x;      // 524288
  int k = i >> 9, d = i & 511;
  const float4* hr = (const float4*)(h + (long)k * HH);
  const float4* wr = (const float4*)(w + (long)d * HH);
  float s = b[d];
  for (int j = 0; j < HH / 4; j++) {
    float4 a = hr[j], bb = wr[j];
    s += a.x * bb.x + a.y * bb.y + a.z * bb.z + a.w * bb.w;
  }
  ct[i] = s;
  cs[i] = sigm_acc(s);
}

// ---- generic tiled SGEMM: C[M,Nc] = Af(A) @ Bf(B) ---------------------------
template <int AM, int BM>
__launch_bounds__(256)
__global__ void gemm64(const float* __restrict__ A, const float* __restrict__ B,
                       const float* __restrict__ dscale, float* __restrict__ C,
                       int M, int Nc, int Kr) {
  __shared__ __align__(16) float as[32][68];   // [kr][m]
  __shared__ __align__(16) float bs[32][68];   // [kr][n]
  int tid = threadIdx.x;
  int tx = tid & 15, ty = tid >> 4;
  int m0 = blockIdx.y * 64, n0 = blockIdx.x * 64;
  float acc[4][4] = {};
  for (int kt = 0; kt < Kr; kt += 32) {
    for (int s = tid; s < 512; s += 256) {
      int m = s >> 3, c4 = (s & 7) << 2;
      int gr = m0 + m, gc = kt + c4;
      float4 v = *(const float4*)&A[(long)gr * Kr + gc];
      float vv[4] = {v.x, v.y, v.z, v.w};
      if (AM == 1) {
#pragma unroll
        for (int q = 0; q < 4; q++) if (gc + q == gr) vv[q] = 1.0f;
      } else if (AM == 2) {
#pragma unroll
        for (int q = 0; q < 4; q++) if (gc + q == gr) vv[q] = 0.0f;
      }
      as[c4 + 0][m] = vv[0]; as[c4 + 1][m] = vv[1];
      as[c4 + 2][m] = vv[2]; as[c4 + 3][m] = vv[3];
    }
    for (int s = tid; s < 512; s += 256) {
      int r = s >> 4, c4 = (s & 15) << 2;
      float4 v = *(const float4*)&B[(long)(kt + r) * Nc + n0 + c4];
      if (BM == 1) {
        float sc = dscale[kt + r];
        v.x *= sc; v.y *= sc; v.z *= sc; v.w *= sc;
      }
      *(float4*)&bs[r][c4] = v;
    }
    __syncthreads();
#pragma unroll
    for (int r = 0; r < 32; r++) {
      float4 a4 = *(const float4*)&as[r][ty * 4];
      float4 b4 = *(const float4*)&bs[r][tx * 4];
      float av[4] = {a4.x, a4.y, a4.z, a4.w};
      float bv[4] = {b4.x, b4.y, b4.z, b4.w};
#pragma unroll
      for (int i = 0; i < 4; i++)
#pragma unroll
        for (int j = 0; j < 4; j++) acc[i][j] += av[i] * bv[j];
    }
    __syncthreads();
  }
#pragma unroll
  for (int i = 0; i < 4; i++) {
    float4 v = make_float4(acc[i][0], acc[i][1], acc[i][2], acc[i][3]);
    *(float4*)&C[(long)(m0 + ty * 4 + i) * Nc + n0 + tx * 4] = v;
  }
}

// ---- row sum-of-squares of ccb -> cn2[1024]; also zero rescue counter -------
__global__ void k_cnorm(const float* __restrict__ ccb, float* __restrict__ cn2,
                        int* __restrict__ rc) {
  if (blockIdx.x == 0 && threadIdx.x == 0) *rc = 0;
  int row = blockIdx.x * 4 + (threadIdx.x >> 6);
  int lane = threadIdx.x & 63;
  const float* r = ccb + (long)row * DD;
  float s = 0.0f;
  for (int q = 0; q < DD; q += 64) { float v = r[lane + q]; s += v * v; }
  for (int off = 32; off > 0; off >>= 1) s += __shfl_down(s, off);
  if (lane == 0) cn2[row] = s;
}

// ---- split fp32 -> bf16 hi + bf16 lo (RNE, manual bit twiddling) ------------
__device__ __forceinline__ ushort bf16_rne(float f, float* back) {
  unsigned int b = __float_as_uint(f);
  unsigned int r = b + 0x7fffu + ((b >> 16) & 1u);
  ushort h = (ushort)(r >> 16);
  *back = __uint_as_float(((unsigned int)h) << 16);
  return h;
}

__global__ void k_split(const float4* __restrict__ src, ushort* __restrict__ hi,
                        ushort* __restrict__ lo, long n4) {
  long i = (long)blockIdx.x * 256 + threadIdx.x;
  if (i >= n4) return;
  float4 v = src[i];
  float vv[4] = {v.x, v.y, v.z, v.w};
  ushort h[4], l[4];
#pragma unroll
  for (int q = 0; q < 4; q++) {
    float back;
    h[q] = bf16_rne(vv[q], &back);
    float rem = vv[q] - back;
    float dummy;
    l[q] = bf16_rne(rem, &dummy);
  }
  ((ushort4*)hi)[i] = make_ushort4(h[0], h[1], h[2], h[3]);
  ((ushort4*)lo)[i] = make_ushort4(l[0], l[1], l[2], l[3]);
}

// ---- MFMA split-bf16 argmin: d2[n,k] = cn2[k] - 2 * x_n . ccb_k -------------
// Block: 256 thr (4 waves 2x2), tile 128 nodes x 128 codes, loops all 8 code-blocks.
// Tracks per-node top-2; nodes with margin < RES_TAU go to the rescue list.
__launch_bounds__(256)
__global__ void k_argmin_mfma(const ushort* __restrict__ xh, const ushort* __restrict__ xl,
                              const ushort* __restrict__ ch, const ushort* __restrict__ cl,
                              const float* __restrict__ cn2, int* __restrict__ idxg,
                              int* __restrict__ rc, int* __restrict__ rlist) {
  // padded rows: 32 data shorts + 8 pad = 40 shorts (80 B) -> 2-way-free b128 reads
  __shared__ __align__(16) ushort xsh[128 * 40];
  __shared__ __align__(16) ushort xsl[128 * 40];
  __shared__ __align__(16) ushort csh[128 * 40];
  __shared__ __align__(16) ushort csl[128 * 40];
  __shared__ float cn2s[KK];
  __shared__ float mm1[2][128], mm2[2][128];
  __shared__ int   mid[2][128];

  int tid = threadIdx.x;
  for (int s = tid; s < KK; s += 256) cn2s[s] = cn2[s];
  long n0 = (long)blockIdx.x * 128;
  int lane = tid & 63, wave = tid >> 6;
  int wy = wave >> 1, wx = wave & 1;
  int col = lane & 15, quad = lane >> 4;

  float m1[16], m2[16]; int id1[16];
#pragma unroll
  for (int s = 0; s < 16; s++) { m1[s] = 3.4e38f; m2[s] = 3.4e38f; id1[s] = 0; }

  const float4v vzero = {0.0f, 0.0f, 0.0f, 0.0f};
  float4v acc[4][4];

  for (int cb = 0; cb < 8; cb++) {
#pragma unroll
    for (int i = 0; i < 4; i++)
#pragma unroll
      for (int j = 0; j < 4; j++) acc[i][j] = vzero;
    long cbase = (long)cb * 128;
    for (int dt = 0; dt < DD; dt += 32) {
      __syncthreads();
      for (int s = tid; s < 512; s += 256) {
        int row = s >> 2, part = s & 3;
        int gc = dt + part * 8;
        int lo = row * 40 + part * 8;
        *(uint4*)&xsh[lo] = *(const uint4*)&xh[(n0 + row) * DD + gc];
        *(uint4*)&xsl[lo] = *(const uint4*)&xl[(n0 + row) * DD + gc];
        *(uint4*)&csh[lo] = *(const uint4*)&ch[(cbase + row) * DD + gc];
        *(uint4*)&csl[lo] = *(const uint4*)&cl[(cbase + row) * DD + gc];
      }
      __syncthreads();
      short8 ah[4], al[4];
#pragma unroll
      for (int i = 0; i < 4; i++) {
        int ro = (wy * 64 + i * 16 + col) * 40 + quad * 8;
        ah[i] = *(const short8*)&xsh[ro];
        al[i] = *(const short8*)&xsl[ro];
      }
#pragma unroll
      for (int j = 0; j < 4; j++) {
        int ro = (wx * 64 + j * 16 + col) * 40 + quad * 8;
        short8 bh = *(const short8*)&csh[ro];
        short8 bl = *(const short8*)&csl[ro];
#pragma unroll
        for (int i = 0; i < 4; i++) {
          acc[i][j] = __builtin_amdgcn_mfma_f32_16x16x32_bf16(ah[i], bh, acc[i][j], 0, 0, 0);
          acc[i][j] = __builtin_amdgcn_mfma_f32_16x16x32_bf16(ah[i], bl, acc[i][j], 0, 0, 0);
          acc[i][j] = __builtin_amdgcn_mfma_f32_16x16x32_bf16(al[i], bh, acc[i][j], 0, 0, 0);
        }
      }
    }
    // epilogue: fold this code-block into per-slot top-2
#pragma unroll
    for (int j = 0; j < 4; j++) {
      int code = cb * 128 + wx * 64 + j * 16 + col;
      float c2 = cn2s[code];
#pragma unroll
      for (int i = 0; i < 4; i++) {
#pragma unroll
        for (int r = 0; r < 4; r++) {
          float v = fmaf(-2.0f, acc[i][j][r], c2);
          int s = i * 4 + r;
          if (v < m1[s] || (v == m1[s] && code < id1[s])) {
            m2[s] = m1[s]; m1[s] = v; id1[s] = code;
          } else if (v < m2[s]) {
            m2[s] = v;
          }
        }
      }
    }
  }
  // cross-lane top-2 merge over the 16 lanes of each quad-group
#pragma unroll
  for (int s = 0; s < 16; s++) {
#pragma unroll
    for (int mask = 1; mask <= 8; mask <<= 1) {
      float om1 = __shfl_xor(m1[s], mask);
      float om2 = __shfl_xor(m2[s], mask);
      int   oid = __shfl_xor(id1[s], mask);
      if (om1 < m1[s] || (om1 == m1[s] && oid < id1[s])) {
        m2[s] = fminf(m1[s], om2); m1[s] = om1; id1[s] = oid;
      } else {
        m2[s] = fminf(m2[s], om1);
      }
    }
  }
  if (col == 0) {   // lanes 0,16,32,48: one writer per quad
#pragma unroll
    for (int s = 0; s < 16; s++) {
      int i = s >> 2, r = s & 3;
      int nl = wy * 64 + i * 16 + quad * 4 + r;
      mm1[wx][nl] = m1[s]; mm2[wx][nl] = m2[s]; mid[wx][nl] = id1[s];
    }
  }
  __syncthreads();
  if (tid < 128) {
    float a1 = mm1[0][tid], a2 = mm2[0][tid]; int ai = mid[0][tid];
    float b1 = mm1[1][tid], b2 = mm2[1][tid]; int bi = mid[1][tid];
    float f1, f2; int fi;
    if (b1 < a1 || (b1 == a1 && bi < ai)) { f1 = b1; fi = bi; f2 = fminf(a1, b2); }
    else                                  { f1 = a1; fi = ai; f2 = fminf(a2, b1); }
    idxg[n0 + tid] = fi;
    if (f2 - f1 < RES_TAU) {
      int p = atomicAdd(rc, 1);
      if (p < RES_CAP) rlist[p] = (int)(n0 + tid);
    }
  }
}

// ---- exact fp32 rescue for near-tie nodes -----------------------------------
__global__ void k_rescue(const float* __restrict__ x, const float* __restrict__ ccb,
                         const float* __restrict__ cn2, const int* __restrict__ rc,
                         const int* __restrict__ rlist, int* __restrict__ idxg) {
  __shared__ float xs[DD];
  __shared__ float bv[256]; __shared__ int bi[256];
  int count = *rc; if (count > RES_CAP) count = RES_CAP;
  int tid = threadIdx.x;
  for (int f = blockIdx.x; f < count; f += gridDim.x) {
    int n = rlist[f];
    for (int s = tid; s < DD; s += 256) xs[s] = x[(long)n * DD + s];
    __syncthreads();
    float best = 3.4e38f; int besti = 0;
    for (int c = tid; c < KK; c += 256) {
      const float4* cr = (const float4*)(ccb + (long)c * DD);
      const float4* xr = (const float4*)xs;
      float dot = 0.0f;
      for (int d = 0; d < DD / 4; d++) {
        float4 a = xr[d], b = cr[d];
        dot += a.x * b.x + a.y * b.y + a.z * b.z + a.w * b.w;
      }
      float v = cn2[c] - 2.0f * dot;
      if (v < best || (v == best && c < besti)) { best = v; besti = c; }
    }
    bv[tid] = best; bi[tid] = besti;
    __syncthreads();
    for (int off = 128; off > 0; off >>= 1) {
      if (tid < off) {
        float ov = bv[tid + off]; int oi = bi[tid + off];
        if (ov < bv[tid] || (ov == bv[tid] && oi < bi[tid])) { bv[tid] = ov; bi[tid] = oi; }
      }
      __syncthreads();
    }
    if (tid == 0) idxg[n] = bi[0];
    __syncthreads();
  }
}

// ---- z gather: z[n,:] = ct[idx[n],:] ----------------------------------------
__global__ void k_gather(const float4* __restrict__ ct4, const int* __restrict__ idxg,
                         float4* __restrict__ z4) {
  long i = (long)blockIdx.x * 256 + threadIdx.x;  // over NN*128 float4
  int n = (int)(i >> 7), c = (int)(i & 127);
  z4[i] = ct4[(long)idxg[n] * 128 + c];
}

// ---- pooled means -----------------------------------------------------------
__global__ void k_pool(const float* __restrict__ x, const float* __restrict__ ccb,
                       const float* __restrict__ kcb, const int* __restrict__ idxg,
                       float* __restrict__ px, float* __restrict__ pc,
                       float* __restrict__ pk) {
  __shared__ int sidx[NPG];
  int g = blockIdx.x, tid = threadIdx.x;   // 512 threads
  if (tid < NPG) sidx[tid] = idxg[g * NPG + tid];
  __syncthreads();
  int d = tid;
  float sx = 0.0f, sc = 0.0f, sk = 0.0f;
  for (int n = 0; n < NPG; n++) {
    sx += x[((long)g * NPG + n) * DD + d];
    long r = (long)sidx[n] * DD + d;
    sc += ccb[r]; sk += kcb[r];
  }
  px[(long)g * DD + d] = sx / 128.0f;
  pc[(long)g * DD + d] = (sx + sc) / 128.0f;
  pk[(long)g * DD + d] = sk / 128.0f;
}

// ---- classifier heads -------------------------------------------------------
__global__ void k_heads(const float* __restrict__ pc, const float* __restrict__ pk,
                        const float* __restrict__ px, const float* __restrict__ w,
                        const float* __restrict__ b, float* __restrict__ cpre,
                        float* __restrict__ kpre, float* __restrict__ ypre) {
  int g = blockIdx.x, t = threadIdx.x;   // 64 threads, 30 active
  if (t >= 30) return;
  int which = t / 10, tt = t % 10;
  const float* src = (which == 0) ? pc : ((which == 1) ? pk : px);
  const float* sr = src + (long)g * DD;
  const float* wr = w + (long)tt * DD;
  float s = 0.0f;
  for (int d = 0; d < DD; d++) s += sr[d] * wr[d];
  s += b[tt];
  float* dst = (which == 0) ? cpre : ((which == 1) ? kpre : ypre);
  dst[g * TT + tt] = s;
}

// ---- x passthrough ----------------------------------------------------------
__global__ void k_copy(const float4* __restrict__ src, float4* __restrict__ dst) {
  long i = (long)blockIdx.x * 256 + threadIdx.x;
  dst[i] = src[i];
}

// ---- per-graph adjacency: sigmoid(norm(Z) @ norm(Z)^T / 0.1) ----------------
__launch_bounds__(256)
__global__ void k_adj(const float* __restrict__ Z, float* __restrict__ Aout) {
  __shared__ float nrm[NPG];
  __shared__ float inv[NPG];
  __shared__ __align__(16) float zs[32][132];  // [d][node]
  int tid = threadIdx.x;
  int g = blockIdx.x;
  const float* base = Z + (long)g * NPG * DD;
  if (tid < NPG) nrm[tid] = 0.0f;
  __syncthreads();
  for (int k = 0; k < 64; k++) {
    long i = (long)k * 256 + tid;                 // float4 index, 16384 total
    int n = (int)(i >> 7);
    float4 v = ((const float4*)base)[i];
    float s = v.x * v.x + v.y * v.y + v.z * v.z + v.w * v.w;
    for (int off = 32; off > 0; off >>= 1) s += __shfl_down(s, off);
    if ((tid & 63) == 0) atomicAdd(&nrm[n], s);
  }
  __syncthreads();
  if (tid < NPG) inv[tid] = 1.0f / fmaxf(sqrtf(nrm[tid]), 1e-12f);
  __syncthreads();
  float acc[8][8] = {};
  int tx = tid & 15, ty = tid >> 4;
  for (int dt = 0; dt < DD; dt += 32) {
    for (int s = tid; s < 1024; s += 256) {
      int n = s >> 3, c4 = (s & 7) << 2;
      float4 v = *(const float4*)&base[(long)n * DD + dt + c4];
      float iv = inv[n];
      zs[c4 + 0][n] = v.x * iv; zs[c4 + 1][n] = v.y * iv;
      zs[c4 + 2][n] = v.z * iv; zs[c4 + 3][n] = v.w * iv;
    }
    __syncthreads();
#pragma unroll 8
    for (int r = 0; r < 32; r++) {
      float rv[8], cv[8];
      *(float4*)&rv[0] = *(const float4*)&zs[r][ty * 8];
      *(float4*)&rv[4] = *(const float4*)&zs[r][ty * 8 + 4];
      *(float4*)&cv[0] = *(const float4*)&zs[r][tx * 8];
      *(float4*)&cv[4] = *(const float4*)&zs[r][tx * 8 + 4];
#pragma unroll
      for (int i = 0; i < 8; i++)
#pragma unroll
        for (int j = 0; j < 8; j++) acc[i][j] += rv[i] * cv[j];
    }
    __syncthreads();
  }
  float* aout = Aout + (long)g * NPG * NPG;
#pragma unroll
  for (int i = 0; i < 8; i++) {
    int rr = ty * 8 + i;
    float o[8];
#pragma unroll
    for (int j = 0; j < 8; j++) o[j] = sigm_fast(acc[i][j] * 10.0f);
    *(float4*)&aout[(long)rr * NPG + tx * 8]     = make_float4(o[0], o[1], o[2], o[3]);
    *(float4*)&aout[(long)rr * NPG + tx * 8 + 4] = make_float4(o[4], o[5], o[6], o[7]);
  }
}

extern "C" void kernel_launch(void* const* d_in, const int* in_sizes, int n_in,
                              void* d_out, int out_size, void* d_ws, size_t ws_size,
                              hipStream_t stream) {
  const float* x      = (const float*)d_in[0];
  const float* cbi    = (const float*)d_in[2];
  const float* fc1w   = (const float*)d_in[3];
  const float* fc1b   = (const float*)d_in[4];
  const float* fc2w   = (const float*)d_in[5];
  const float* fc2b   = (const float*)d_in[6];
  const float* causal = (const float*)d_in[7];
  const float* clsw   = (const float*)d_in[8];
  const float* clsb   = (const float*)d_in[9];
  float* out = (float*)d_out;

  float* cpre = out + OFF_CPRE;
  float* kpre = out + OFF_KPRE;
  float* ypre = out + OFF_YPRE;

  // scratch carved out of the A_ori region (overwritten by final k_adj)
  float* scr  = out + OFF_AORI;
  float* h    = scr;
  float* cs   = scr + 131072L;
  float* tmp2 = scr + 655360L;
  float* ccb  = scr + 1179648L;
  float* kcb  = scr + 1703936L;
  float* cn2  = scr + 2228224L;
  int*   idxg = (int*)(scr + 2229248L);
  float* pk   = scr + 2294784L;
  float* dv   = scr + 2556928L;
  ushort* ch  = (ushort*)(scr + 2557952L);  // 1024x512 bf16 hi (262144 floats)
  ushort* cl  = (ushort*)(scr + 2820096L);  // 1024x512 bf16 lo
  int*   rc   = (int*)(scr + 3082240L);     // rescue counter
  int*   rlist= (int*)(scr + 3082496L);     // rescue list (65536 ints)
  float* ct   = out + OFF_AREC;             // lives in A_rec region until gather done
  // x hi/lo split lives in the X output region until k_copy (runs after argmin+rescue)
  ushort* xh  = (ushort*)(out + OFF_X);                 // 65536x512 bf16 hi
  ushort* xl  = (ushort*)(out + OFF_X + 16777216L);     // 65536x512 bf16 lo

  k_diagmask<<<4096, 256, 0, stream>>>(causal, out + OFF_CD, out + OFF_CM, dv);
  k_fc1<<<512, 256, 0, stream>>>(cbi, fc1w, fc1b, h);
  k_fc2<<<2048, 256, 0, stream>>>(h, fc2w, fc2b, ct, cs);
  gemm64<2, 0><<<dim3(8, 16), 256, 0, stream>>>(causal, cs,   nullptr, tmp2, KK, DD, KK);
  gemm64<1, 1><<<dim3(8, 16), 256, 0, stream>>>(causal, cs,   dv,      ccb,  KK, DD, KK);
  gemm64<1, 0><<<dim3(8, 16), 256, 0, stream>>>(causal, tmp2, nullptr, kcb,  KK, DD, KK);
  k_cnorm<<<256, 256, 0, stream>>>(ccb, cn2, rc);
  k_split<<<32768, 256, 0, stream>>>((const float4*)x, xh, xl, 8388608L);
  k_split<<<512, 256, 0, stream>>>((const float4*)ccb, ch, cl, 131072L);
  k_argmin_mfma<<<512, 256, 0, stream>>>(xh, xl, ch, cl, cn2, idxg, rc, rlist);
  k_rescue<<<128, 256, 0, stream>>>(x, ccb, cn2, rc, rlist, idxg);
  k_gather<<<32768, 256, 0, stream>>>((const float4*)ct, idxg, (float4*)(out + OFF_Z));
  k_pool<<<512, 512, 0, stream>>>(x, ccb, kcb, idxg, out + OFF_PX, out + OFF_PC, pk);
  k_heads<<<512, 64, 0, stream>>>(out + OFF_PC, pk, out + OFF_PX, clsw, clsb, cpre, kpre, ypre);
  k_copy<<<32768, 256, 0, stream>>>((const float4*)x, (float4*)(out + OFF_X));
  k_adj<<<512, 256, 0, stream>>>(out + OFF_Z, out + OFF_AREC);  // overwrites ct (done)
  k_adj<<<512, 256, 0, stream>>>(x, out + OFF_AORI);            // overwrites scratch (done)
}